// Round 1
// baseline (774.895 us; speedup 1.0000x reference)
//
#include <hip/hip_runtime.h>

// ---------------------------------------------------------------------------
// DMSRStyleConv: style-modulated, demodulated 3x3x3 conv (StyleGAN-style),
// B=8, Cin=Cout=64, grid 48^3 -> 46^3 VALID, fp32 in/out.
//
// Pipeline (all on `stream`, all state recomputed every launch):
//   1) sd_kernel : s[b][ci] = style @ style_w^T + style_b ; d[b][co] = demod
//   2) wq_kernel : wq[b][tap][cout][ci] = bf16(weight*s*d)   (A-operand layout)
//   3) xT_kernel : xT[b][z][y][x][ci]   = bf16(x)            (ci-minor for B-frags)
//   4) conv_kernel: implicit-GEMM conv, 16x16x32 bf16 MFMA, fp32 accum + bias
// ---------------------------------------------------------------------------

typedef __bf16 bf16x8 __attribute__((ext_vector_type(8)));
typedef float  f32x4  __attribute__((ext_vector_type(4)));

static constexpr int   B_   = 8;
static constexpr int   CIN  = 64;
static constexpr int   COUT = 64;
static constexpr int   S_   = 512;
static constexpr int   G_   = 48;
static constexpr int   O_   = 46;
static constexpr int   TAPS = 27;
static constexpr int   SPI  = G_ * G_ * G_;   // 110592
static constexpr int   SPO  = O_ * O_ * O_;   // 97336
static constexpr float EPSV = 1e-8f;

// workspace layout (bytes)
static constexpr size_t XT_OFF   = 0;
static constexpr size_t XT_BYTES = (size_t)B_ * SPI * CIN * 2;      // 113,246,208
static constexpr size_t WQ_OFF   = XT_OFF + XT_BYTES;
static constexpr size_t WQ_BYTES = (size_t)B_ * TAPS * COUT * CIN * 2; // 1,769,472
static constexpr size_t S_OFF    = WQ_OFF + WQ_BYTES;
static constexpr size_t D_OFF    = S_OFF + 2048;
// total ~115 MB of d_ws used

// fp32 -> bf16 with round-to-nearest-even (bit-level, no hip_bf16 API needed)
__device__ __forceinline__ unsigned short f2bf(float f) {
    unsigned int u = __float_as_uint(f);
    u = (u + 0x7fffu + ((u >> 16) & 1u)) >> 16;
    return (unsigned short)u;
}

// ---------------------------------------------------------------------------
// 1) style scales s[b][ci] and demod factors d[b][co]; grid=8, block=256
// ---------------------------------------------------------------------------
__global__ void sd_kernel(const float* __restrict__ style,
                          const float* __restrict__ style_w,
                          const float* __restrict__ style_b,
                          const float* __restrict__ weight,
                          float* __restrict__ s_out,
                          float* __restrict__ d_out)
{
    const int b = blockIdx.x, t = threadIdx.x;
    const int g = t >> 2, part = t & 3;     // g: ci (then cout), 4 lanes/row
    __shared__ float s_sh[64];

    // s[g] = dot(style[b,:], style_w[g,:]) + style_b[g]
    float acc = 0.f;
    const float* st = style + b * S_ + part * 128;
    const float* sw = style_w + g * S_ + part * 128;
    for (int k = 0; k < 128; ++k) acc += st[k] * sw[k];
    acc += __shfl_xor(acc, 1);
    acc += __shfl_xor(acc, 2);
    const float sv = acc + style_b[g];
    if (part == 0) s_sh[g] = sv;
    __syncthreads();

    // d[g] = rsqrt(sum_{ci,tap} (weight[g][ci][tap] * s[ci])^2 + eps)
    float v = 0.f;
    for (int j = 0; j < 16; ++j) {
        const int ci = part * 16 + j;
        const float ss = s_sh[ci];
        const float* wp = weight + (g * 64 + ci) * 27;
#pragma unroll
        for (int tp = 0; tp < 27; ++tp) { const float wv = wp[tp] * ss; v += wv * wv; }
    }
    v += __shfl_xor(v, 1);
    v += __shfl_xor(v, 2);
    if (part == 0) {
        s_out[b * 64 + g] = s_sh[g];
        d_out[b * 64 + g] = rsqrtf(v + EPSV);
    }
}

// ---------------------------------------------------------------------------
// 2) modulated bf16 weights wq[b][tap][cout][ci]; grid=8*27, block=256
// ---------------------------------------------------------------------------
__global__ void wq_kernel(const float* __restrict__ weight,
                          const float* __restrict__ s,
                          const float* __restrict__ d,
                          unsigned short* __restrict__ wq)
{
    const int blk = blockIdx.x;
    const int b = blk / 27, tap = blk - b * 27;
    const int t = threadIdx.x;
    const int co = t >> 2, ci0 = (t & 3) * 16;
    const float dd = d[b * 64 + co];
    unsigned short* dst = wq + ((size_t)(b * 27 + tap)) * 4096 + co * 64 + ci0;
#pragma unroll
    for (int j = 0; j < 16; ++j) {
        const int ci = ci0 + j;
        const float wv = weight[(co * 64 + ci) * 27 + tap] * s[b * 64 + ci] * dd;
        dst[j] = f2bf(wv);
    }
}

// ---------------------------------------------------------------------------
// 3) x [b][ci][sp] fp32  ->  xT [b][sp][ci] bf16 ; grid=8*1728, block=256
//    64-spatial x 64-ci tiles via LDS (coalesced both sides)
// ---------------------------------------------------------------------------
__global__ void xT_kernel(const float* __restrict__ x,
                          unsigned short* __restrict__ xT)
{
    const int blk = blockIdx.x;
    const int b = blk / 1728;
    const int sp0 = (blk - b * 1728) * 64;
    const int t = threadIdx.x;
    __shared__ float tile[64][65];          // +1 pad: conflict-free

    const int spl = t & 63;
    const int c4 = t >> 6;                  // 0..3
#pragma unroll
    for (int p = 0; p < 16; ++p) {
        const int ci = c4 * 16 + p;
        tile[ci][spl] = x[((size_t)b * 64 + ci) * SPI + sp0 + spl];
    }
    __syncthreads();

    const int ci2 = (t & 31) * 2;           // lanes cover ci (2 each) for fixed sp
    const int sp8 = t >> 5;                 // 0..7
#pragma unroll
    for (int p = 0; p < 8; ++p) {
        const int sp = sp8 * 8 + p;
        const unsigned int lo = f2bf(tile[ci2][sp]);
        const unsigned int hi = f2bf(tile[ci2 + 1][sp]);
        *(unsigned int*)(xT + ((size_t)b * SPI + sp0 + sp) * 64 + ci2) = lo | (hi << 16);
    }
}

// ---------------------------------------------------------------------------
// 4) the conv. Block = one (b, 4z x 4y x 8x) tile of outputs, all 64 cout.
//    LDS x-tile: 6x6x10 spatial x 64ci bf16, row stride 144 B (16 B pad -> all
//    32 banks covered by ds_read_b128 frag reads AND staging writes).
//    Per tap: A = wq[b][tap] (64x64, double-buffered 9.2 KB), B = shifted
//    window of x-tile; K=64 -> 2 MFMA k-steps; wave tile 64M x 32N.
// ---------------------------------------------------------------------------
#define XTILE_B 51840                       // 360 sp * 144 B
#define WBUF_B  9216                        // 64 rows * 144 B

__global__ __launch_bounds__(256, 2) void conv_kernel(
    const unsigned short* __restrict__ xT,   // [8][48][48][48][64] bf16 bits
    const unsigned short* __restrict__ wq,   // [8][27][64][64]     bf16 bits
    const float* __restrict__ bias,          // [64]
    float* __restrict__ out)                 // [8][64][46][46][46] fp32
{
    __shared__ __align__(16) char lds[XTILE_B + 2 * WBUF_B];
    char* const xs  = lds;
    char* const ws0 = lds + XTILE_B;

    const int t  = threadIdx.x;
    const int xt = blockIdx.x;               // 0..5
    const int yt = blockIdx.y;               // 0..11
    const int bz = blockIdx.z;               // 0..95
    const int b  = bz / 12, zt = bz - b * 12;
    // overlapping tiles -> no store masking; duplicate stores write identical values
    const int x0 = (xt < 5)  ? xt * 8 : 38;
    const int y0 = (yt < 11) ? yt * 4 : 42;
    const int z0 = (zt < 11) ? zt * 4 : 42;

    const unsigned short* const xb = xT + (size_t)b * (SPI * CIN);
    const unsigned short* const wb = wq + (size_t)b * (TAPS * 4096);

    // ---- stage x-tile: 360 sp x 8 ci-groups of 16 B --------------------------
    for (int i = t; i < 2880; i += 256) {
        const int sp = i >> 3, cg = i & 7;
        const int iz = sp / 60;
        const int r1 = sp - iz * 60;
        const int iy = r1 / 10;
        const int ix = r1 - iy * 10;
        const uint4 v = *(const uint4*)(xb + ((((z0 + iz) * 48) + (y0 + iy)) * 48 + (x0 + ix)) * 64 + cg * 8);
        *(uint4*)(xs + sp * 144 + cg * 16) = v;
    }
    // ---- stage weights for tap 0 into buffer 0 -------------------------------
    {
        const uint4 v0 = *(const uint4*)(wb + t * 8);
        const uint4 v1 = *(const uint4*)(wb + (t + 256) * 8);
        *(uint4*)(ws0 + (t >> 3) * 144 + (t & 7) * 16) = v0;
        *(uint4*)(ws0 + ((t + 256) >> 3) * 144 + (t & 7) * 16) = v1;
    }
    __syncthreads();

    // lane geometry: wave w covers n = w*32 .. w*32+31; dz=w, dy=(n>>3)&3, dx=n&7
    const int w = t >> 6, l = t & 63, q = l >> 4, l16 = l & 15;
    const int dx = l16 & 7, dy0 = l16 >> 3, dz = w;
    const int spA = (dz * 6 + dy0) * 10 + dx;
    const int bo0 = spA * 144 + q * 16;      // nt=0 fragment base
    const int bo1 = bo0 + 20 * 144;          // nt=1: dy+2 -> +20 spatial rows
    const int ao  = l16 * 144 + q * 16;      // A fragment base (row = cout%16)

    f32x4 acc[8];
#pragma unroll
    for (int i = 0; i < 8; ++i) acc[i] = (f32x4){0.f, 0.f, 0.f, 0.f};

    int buf = 0;
#pragma unroll 1
    for (int tap = 0; tap < TAPS; ++tap) {
        // prefetch next tap's weights (global -> regs) while we compute
        uint4 pv0, pv1;
        const bool pre = (tap < TAPS - 1);
        if (pre) {
            pv0 = *(const uint4*)(wb + (tap + 1) * 4096 + t * 8);
            pv1 = *(const uint4*)(wb + (tap + 1) * 4096 + (t + 256) * 8);
        }
        const int kz = tap / 9;
        const int r2 = tap - kz * 9;
        const int ky = r2 / 3;
        const int kx = r2 - ky * 3;
        const int toff = (kz * 60 + ky * 10 + kx) * 144;
        const char* wc = ws0 + buf * WBUF_B;

#pragma unroll
        for (int ks = 0; ks < 2; ++ks) {
            const int ko = ks * 64;          // +32 ci = +64 B
            const bf16x8 a0 = *(const bf16x8*)(wc + ao + ko);
            const bf16x8 a1 = *(const bf16x8*)(wc + ao + ko + 2304);
            const bf16x8 a2 = *(const bf16x8*)(wc + ao + ko + 4608);
            const bf16x8 a3 = *(const bf16x8*)(wc + ao + ko + 6912);
            const bf16x8 b0 = *(const bf16x8*)(xs + toff + bo0 + ko);
            const bf16x8 b1 = *(const bf16x8*)(xs + toff + bo1 + ko);
            acc[0] = __builtin_amdgcn_mfma_f32_16x16x32_bf16(a0, b0, acc[0], 0, 0, 0);
            acc[1] = __builtin_amdgcn_mfma_f32_16x16x32_bf16(a0, b1, acc[1], 0, 0, 0);
            acc[2] = __builtin_amdgcn_mfma_f32_16x16x32_bf16(a1, b0, acc[2], 0, 0, 0);
            acc[3] = __builtin_amdgcn_mfma_f32_16x16x32_bf16(a1, b1, acc[3], 0, 0, 0);
            acc[4] = __builtin_amdgcn_mfma_f32_16x16x32_bf16(a2, b0, acc[4], 0, 0, 0);
            acc[5] = __builtin_amdgcn_mfma_f32_16x16x32_bf16(a2, b1, acc[5], 0, 0, 0);
            acc[6] = __builtin_amdgcn_mfma_f32_16x16x32_bf16(a3, b0, acc[6], 0, 0, 0);
            acc[7] = __builtin_amdgcn_mfma_f32_16x16x32_bf16(a3, b1, acc[7], 0, 0, 0);
        }

        if (pre) {
            char* wn = ws0 + (buf ^ 1) * WBUF_B;
            *(uint4*)(wn + (t >> 3) * 144 + (t & 7) * 16) = pv0;
            *(uint4*)(wn + ((t + 256) >> 3) * 144 + (t & 7) * 16) = pv1;
        }
        __syncthreads();
        buf ^= 1;
    }

    // ---- epilogue: C/D layout col=lane&15 (n), row=q*4+r (cout%16) -----------
    const size_t ob = (size_t)b * 64 * SPO;
    const int oz = z0 + dz;
    const int ox = x0 + dx;
#pragma unroll
    for (int mt = 0; mt < 4; ++mt) {
#pragma unroll
        for (int nt = 0; nt < 2; ++nt) {
            const int oy = y0 + dy0 + nt * 2;
            const f32x4 v = acc[mt * 2 + nt];
            const size_t sp_out = (size_t)oz * 2116 + oy * 46 + ox;
#pragma unroll
            for (int r = 0; r < 4; ++r) {
                const int co = mt * 16 + q * 4 + r;
                out[ob + (size_t)co * SPO + sp_out] = v[r] + bias[co];
            }
        }
    }
}

// ---------------------------------------------------------------------------
extern "C" void kernel_launch(void* const* d_in, const int* in_sizes, int n_in,
                              void* d_out, int out_size, void* d_ws, size_t ws_size,
                              hipStream_t stream)
{
    const float* x       = (const float*)d_in[0];
    const float* style   = (const float*)d_in[1];
    const float* weight  = (const float*)d_in[2];
    const float* bias    = (const float*)d_in[3];
    const float* style_w = (const float*)d_in[4];
    const float* style_b = (const float*)d_in[5];
    float* out = (float*)d_out;

    char* ws = (char*)d_ws;
    unsigned short* xT  = (unsigned short*)(ws + XT_OFF);
    unsigned short* wqp = (unsigned short*)(ws + WQ_OFF);
    float* sbuf = (float*)(ws + S_OFF);
    float* dbuf = (float*)(ws + D_OFF);

    hipLaunchKernelGGL(sd_kernel, dim3(B_), dim3(256), 0, stream,
                       style, style_w, style_b, weight, sbuf, dbuf);
    hipLaunchKernelGGL(wq_kernel, dim3(B_ * TAPS), dim3(256), 0, stream,
                       weight, sbuf, dbuf, wqp);
    hipLaunchKernelGGL(xT_kernel, dim3(B_ * (SPI / 64)), dim3(256), 0, stream,
                       x, xT);
    hipLaunchKernelGGL(conv_kernel, dim3(6, 12, 96), dim3(256), 0, stream,
                       xT, wqp, bias, out);
}

// Round 2
// 688.352 us; speedup vs baseline: 1.1257x; 1.1257x over previous
//
#include <hip/hip_runtime.h>

// ---------------------------------------------------------------------------
// DMSRStyleConv v2: style-modulated, demodulated 3x3x3 conv.
// B=8, Cin=Cout=64, 48^3 -> 46^3 VALID, fp32 in/out.
//
//   1) s_kernel  : s[b][ci]  = style @ style_w^T + style_b      (512 blk x 64)
//   2) d_kernel  : d[b][co]  = rsqrt(sum (w*s)^2 + eps)         (512 blk x 64)
//   3) wq_kernel : wq[b][kc][tap][co][ci32] = bf16(w*s*d)       (216 blk x 256)
//   4) xT_kernel : xT[b][z][y][x][ci] = bf16(x)                 (13824 blk)
//   5) conv      : implicit GEMM, wave tile 64co x 64sp, K split in two
//                  32-ci chunks (LDS x-tile 51.8 KB, 2 blocks/CU),
//                  stride-80 LDS rows (conflict-free b128), 16x16x32 bf16 MFMA
// ---------------------------------------------------------------------------

typedef __bf16 bf16x8 __attribute__((ext_vector_type(8)));
typedef float  f32x4  __attribute__((ext_vector_type(4)));

static constexpr int   B_   = 8;
static constexpr int   S_   = 512;
static constexpr int   G_   = 48;
static constexpr int   O_   = 46;
static constexpr int   TAPS = 27;
static constexpr int   SPI  = G_ * G_ * G_;   // 110592
static constexpr int   SPO  = O_ * O_ * O_;   // 97336
static constexpr float EPSV = 1e-8f;

// workspace layout (bytes)
static constexpr size_t XT_OFF   = 0;
static constexpr size_t XT_BYTES = (size_t)B_ * SPI * 64 * 2;        // 113 MB
static constexpr size_t WQ_OFF   = XT_OFF + XT_BYTES;
static constexpr size_t WQ_BYTES = (size_t)B_ * 2 * TAPS * 64 * 32 * 2; // 1.77 MB
static constexpr size_t S_OFF    = WQ_OFF + WQ_BYTES;
static constexpr size_t D_OFF    = S_OFF + 2048;

__device__ __forceinline__ unsigned short f2bf(float f) {
    unsigned int u = __float_as_uint(f);
    u = (u + 0x7fffu + ((u >> 16) & 1u)) >> 16;
    return (unsigned short)u;
}

// ---------------------------------------------------------------------------
// 1) s[b][g] = dot(style[b,:], style_w[g,:]) + style_b[g]; grid 512, block 64
// ---------------------------------------------------------------------------
__global__ void s_kernel(const float* __restrict__ style,
                         const float* __restrict__ style_w,
                         const float* __restrict__ style_b,
                         float* __restrict__ s_out)
{
    const int bg = blockIdx.x, b = bg >> 6, g = bg & 63, l = threadIdx.x;
    const float4* sp = (const float4*)(style + b * S_);
    const float4* wp = (const float4*)(style_w + g * S_);
    const float4 a0 = sp[l * 2], a1 = sp[l * 2 + 1];
    const float4 b0 = wp[l * 2], b1 = wp[l * 2 + 1];
    float acc = a0.x * b0.x + a0.y * b0.y + a0.z * b0.z + a0.w * b0.w
              + a1.x * b1.x + a1.y * b1.y + a1.z * b1.z + a1.w * b1.w;
#pragma unroll
    for (int m = 1; m <= 32; m <<= 1) acc += __shfl_xor(acc, m);
    if (l == 0) s_out[bg] = acc + style_b[g];
}

// ---------------------------------------------------------------------------
// 2) d[b][co] = rsqrt(sum_{ci,tap}(w[co][ci][tap]*s[b][ci])^2+eps); 512 x 64
// ---------------------------------------------------------------------------
__global__ void d_kernel(const float* __restrict__ weight,
                         const float* __restrict__ s,
                         float* __restrict__ d_out)
{
    const int bc = blockIdx.x, b = bc >> 6, co = bc & 63, ci = threadIdx.x;
    const float sv = s[b * 64 + ci];
    const float* wp = weight + (co * 64 + ci) * TAPS;
    float v = 0.f;
#pragma unroll
    for (int i = 0; i < TAPS; ++i) { const float t = wp[i] * sv; v += t * t; }
#pragma unroll
    for (int m = 1; m <= 32; m <<= 1) v += __shfl_xor(v, m);
    if (ci == 0) d_out[bc] = rsqrtf(v + EPSV);
}

// ---------------------------------------------------------------------------
// 3) wq[b][kc][tap][co][ci32] bf16; grid 216, block 256
// ---------------------------------------------------------------------------
__global__ void wq_kernel(const float* __restrict__ weight,
                          const float* __restrict__ s,
                          const float* __restrict__ d,
                          unsigned short* __restrict__ wq)
{
    const int blk = blockIdx.x;
    const int b = blk / 27, tap = blk - b * 27;
    const int t = threadIdx.x;
    const int co = t >> 2, j4 = t & 3;
    const float dd = d[b * 64 + co];
#pragma unroll
    for (int j = 0; j < 16; ++j) {
        const int ci = j4 * 16 + j;
        const float wv = weight[(co * 64 + ci) * TAPS + tap] * s[b * 64 + ci] * dd;
        const int kc = ci >> 5, c32 = ci & 31;
        wq[((size_t)((b * 2 + kc) * 27 + tap)) * 2048 + co * 32 + c32] = f2bf(wv);
    }
}

// ---------------------------------------------------------------------------
// 4) x [b][ci][sp] fp32 -> xT [b][sp][ci] bf16; grid 8*1728, block 256
// ---------------------------------------------------------------------------
__global__ void xT_kernel(const float* __restrict__ x,
                          unsigned short* __restrict__ xT)
{
    const int blk = blockIdx.x;
    const int b = blk / 1728;
    const int sp0 = (blk - b * 1728) * 64;
    const int t = threadIdx.x;
    __shared__ float tile[64][65];

    const int spl = t & 63;
    const int c4 = t >> 6;
#pragma unroll
    for (int p = 0; p < 16; ++p) {
        const int ci = c4 * 16 + p;
        tile[ci][spl] = x[((size_t)b * 64 + ci) * SPI + sp0 + spl];
    }
    __syncthreads();

    const int ci8 = (t & 7) * 8;
    const int spq = t >> 3;                  // 0..31
#pragma unroll
    for (int p = 0; p < 2; ++p) {
        const int sp = spq + 32 * p;
        unsigned int u[4];
#pragma unroll
        for (int k = 0; k < 4; ++k) {
            const unsigned int lo = f2bf(tile[ci8 + 2 * k][sp]);
            const unsigned int hi = f2bf(tile[ci8 + 2 * k + 1][sp]);
            u[k] = lo | (hi << 16);
        }
        uint4 v; v.x = u[0]; v.y = u[1]; v.z = u[2]; v.w = u[3];
        *(uint4*)(xT + ((size_t)b * SPI + sp0 + sp) * 64 + ci8) = v;
    }
}

// ---------------------------------------------------------------------------
// 5) conv. Block = (b, 4z x 4y x 16x) outputs x 64 cout; 4 waves, each wave
//    = all 64 cout x 64 spatial (its z-slice). K (64 ci) split in 2 chunks
//    of 32; x-tile 18x6x6 sp x 32ci bf16, row stride 80 B (conflict-free).
//    Per tap: 4 A-frags x 4 B-frags -> 16 MFMA per 8 ds_read_b128.
// ---------------------------------------------------------------------------
#define XST     80
#define XTILE_B (648 * 80)     // 51840
#define WST     80
#define WBUF_B  (64 * 80)      // 5120

__global__ __launch_bounds__(256, 2) void conv_kernel(
    const unsigned short* __restrict__ xT,   // [8][48][48][48][64] bf16 bits
    const unsigned short* __restrict__ wq,   // [8][2][27][64][32]  bf16 bits
    const float* __restrict__ bias,          // [64]
    float* __restrict__ out)                 // [8][64][46][46][46] fp32
{
    __shared__ __align__(16) char lds[XTILE_B + 2 * WBUF_B];
    char* const xs  = lds;
    char* const ws0 = lds + XTILE_B;

    const int t  = threadIdx.x;
    const int xt = blockIdx.x;               // 0..2
    const int yt = blockIdx.y;               // 0..11
    const int bz = blockIdx.z;               // 0..95
    const int b  = bz / 12, zt = bz - b * 12;
    const int x0 = xt * 16;                  // {0,16,32}; ox>=46 masked
    const int y0 = (yt < 11) ? yt * 4 : 42;  // overlap tiles: dup stores identical
    const int z0 = (zt < 11) ? zt * 4 : 42;

    const unsigned short* const xb = xT + (size_t)b * (SPI * 64);
    const unsigned short* const wb = wq + (size_t)b * (2 * TAPS * 2048);

    const int w = t >> 6, l = t & 63, kg = l >> 4, l16 = l & 15;
    const int ao    = l16 * WST + kg * 16;               // A frag: row co%16
    const int bbase = (w * 108 + l16) * XST + kg * 16;   // B frag: dz=w, dx=l16

    f32x4 acc[16];
#pragma unroll
    for (int i = 0; i < 16; ++i) acc[i] = (f32x4){0.f, 0.f, 0.f, 0.f};

#pragma unroll 1
    for (int kc = 0; kc < 2; ++kc) {
        // ---- stage x chunk: 648 sp x 32 ci --------------------------------
        for (int i = t; i < 2592; i += 256) {
            const int sp = i >> 2, cg = i & 3;
            const int iz = sp / 108;
            const int r1 = sp - iz * 108;
            const int iy = r1 / 18;
            const int ix = r1 - iy * 18;
            int gx = x0 + ix; if (gx > 47) gx = 47;      // clamp (masked outputs only)
            const uint4 v = *(const uint4*)(xb +
                ((((z0 + iz) * 48) + (y0 + iy)) * 48 + gx) * 64 + kc * 32 + cg * 8);
            *(uint4*)(xs + sp * XST + cg * 16) = v;
        }
        // ---- stage weights tap0 -> buf0 -----------------------------------
        {
            const uint4 v = *(const uint4*)(wb + (size_t)kc * TAPS * 2048 + t * 8);
            *(uint4*)(ws0 + (t >> 2) * WST + (t & 3) * 16) = v;
        }
        __syncthreads();

        int buf = 0;
#pragma unroll 1
        for (int tap = 0; tap < TAPS; ++tap) {
            uint4 pv;
            const bool pre = (tap < TAPS - 1);
            if (pre)
                pv = *(const uint4*)(wb + (size_t)(kc * TAPS + tap + 1) * 2048 + t * 8);
            const int kz = tap / 9;
            const int r2 = tap - kz * 9;
            const int ky = r2 / 3;
            const int kx = r2 - ky * 3;
            const int toff = ((kz * 6 + ky) * 18 + kx) * XST;
            const char* wc = ws0 + buf * WBUF_B;

            bf16x8 a0 = *(const bf16x8*)(wc + ao);
            bf16x8 a1 = *(const bf16x8*)(wc + ao + 16 * WST);
            bf16x8 a2 = *(const bf16x8*)(wc + ao + 32 * WST);
            bf16x8 a3 = *(const bf16x8*)(wc + ao + 48 * WST);
            bf16x8 b0 = *(const bf16x8*)(xs + toff + bbase);
            bf16x8 b1 = *(const bf16x8*)(xs + toff + bbase + 18 * XST);
            bf16x8 b2 = *(const bf16x8*)(xs + toff + bbase + 36 * XST);
            bf16x8 b3 = *(const bf16x8*)(xs + toff + bbase + 54 * XST);

            acc[0]  = __builtin_amdgcn_mfma_f32_16x16x32_bf16(a0, b0, acc[0],  0, 0, 0);
            acc[1]  = __builtin_amdgcn_mfma_f32_16x16x32_bf16(a0, b1, acc[1],  0, 0, 0);
            acc[2]  = __builtin_amdgcn_mfma_f32_16x16x32_bf16(a0, b2, acc[2],  0, 0, 0);
            acc[3]  = __builtin_amdgcn_mfma_f32_16x16x32_bf16(a0, b3, acc[3],  0, 0, 0);
            acc[4]  = __builtin_amdgcn_mfma_f32_16x16x32_bf16(a1, b0, acc[4],  0, 0, 0);
            acc[5]  = __builtin_amdgcn_mfma_f32_16x16x32_bf16(a1, b1, acc[5],  0, 0, 0);
            acc[6]  = __builtin_amdgcn_mfma_f32_16x16x32_bf16(a1, b2, acc[6],  0, 0, 0);
            acc[7]  = __builtin_amdgcn_mfma_f32_16x16x32_bf16(a1, b3, acc[7],  0, 0, 0);
            acc[8]  = __builtin_amdgcn_mfma_f32_16x16x32_bf16(a2, b0, acc[8],  0, 0, 0);
            acc[9]  = __builtin_amdgcn_mfma_f32_16x16x32_bf16(a2, b1, acc[9],  0, 0, 0);
            acc[10] = __builtin_amdgcn_mfma_f32_16x16x32_bf16(a2, b2, acc[10], 0, 0, 0);
            acc[11] = __builtin_amdgcn_mfma_f32_16x16x32_bf16(a2, b3, acc[11], 0, 0, 0);
            acc[12] = __builtin_amdgcn_mfma_f32_16x16x32_bf16(a3, b0, acc[12], 0, 0, 0);
            acc[13] = __builtin_amdgcn_mfma_f32_16x16x32_bf16(a3, b1, acc[13], 0, 0, 0);
            acc[14] = __builtin_amdgcn_mfma_f32_16x16x32_bf16(a3, b2, acc[14], 0, 0, 0);
            acc[15] = __builtin_amdgcn_mfma_f32_16x16x32_bf16(a3, b3, acc[15], 0, 0, 0);

            if (pre) {
                char* wn = ws0 + (buf ^ 1) * WBUF_B;
                *(uint4*)(wn + (t >> 2) * WST + (t & 3) * 16) = pv;
            }
            __syncthreads();
            buf ^= 1;
        }
    }

    // ---- epilogue: C/D col = l16 = dx (n), row = kg*4+r = co%16 -------------
    const size_t ob = (size_t)b * 64 * SPO;
    const int oz = z0 + w;
    const int ox = x0 + l16;
    const bool xok = (ox < O_);
    if (xok) {
#pragma unroll
        for (int g = 0; g < 4; ++g) {
#pragma unroll
            for (int nt = 0; nt < 4; ++nt) {
                const int oy = y0 + nt;
                const f32x4 v = acc[g * 4 + nt];
                const size_t so = (size_t)oz * 2116 + oy * 46 + ox;
#pragma unroll
                for (int r = 0; r < 4; ++r) {
                    const int co = g * 16 + kg * 4 + r;
                    out[ob + (size_t)co * SPO + so] = v[r] + bias[co];
                }
            }
        }
    }
}

// ---------------------------------------------------------------------------
extern "C" void kernel_launch(void* const* d_in, const int* in_sizes, int n_in,
                              void* d_out, int out_size, void* d_ws, size_t ws_size,
                              hipStream_t stream)
{
    const float* x       = (const float*)d_in[0];
    const float* style   = (const float*)d_in[1];
    const float* weight  = (const float*)d_in[2];
    const float* bias    = (const float*)d_in[3];
    const float* style_w = (const float*)d_in[4];
    const float* style_b = (const float*)d_in[5];
    float* out = (float*)d_out;

    char* ws = (char*)d_ws;
    unsigned short* xT  = (unsigned short*)(ws + XT_OFF);
    unsigned short* wqp = (unsigned short*)(ws + WQ_OFF);
    float* sbuf = (float*)(ws + S_OFF);
    float* dbuf = (float*)(ws + D_OFF);

    hipLaunchKernelGGL(s_kernel, dim3(512), dim3(64), 0, stream,
                       style, style_w, style_b, sbuf);
    hipLaunchKernelGGL(d_kernel, dim3(512), dim3(64), 0, stream,
                       weight, sbuf, dbuf);
    hipLaunchKernelGGL(wq_kernel, dim3(216), dim3(256), 0, stream,
                       weight, sbuf, dbuf, wqp);
    hipLaunchKernelGGL(xT_kernel, dim3(B_ * (SPI / 64)), dim3(256), 0, stream,
                       x, xT);
    hipLaunchKernelGGL(conv_kernel, dim3(3, 12, 96), dim3(256), 0, stream,
                       xT, wqp, bias, out);
}